// Round 1
// baseline (421.192 us; speedup 1.0000x reference)
//
#include <hip/hip_runtime.h>
#include <hip/hip_bf16.h>

using bf16 = __hip_bfloat16;
typedef __attribute__((ext_vector_type(8))) short bf16x8;
typedef __attribute__((ext_vector_type(4))) float f32x4;

constexpr int Bz  = 2;
constexpr int SEQ = 2048;
constexpr int DM  = 2048;
constexpr int H   = 16;
constexpr int HD  = 128;
constexpr long MROWS = (long)Bz * SEQ;   // 4096
constexpr int EQ  = 3 * DM;              // 6144
constexpr float QSCALE = 0.08838834764831845f; // 1/sqrt(128)

__device__ __forceinline__ float bf2f(bf16 x) { return __bfloat162float(x); }
__device__ __forceinline__ bf16  f2bf(float x) { return __float2bfloat16(x); }

__device__ __forceinline__ void gl_lds16(const void* g, void* l) {
  __builtin_amdgcn_global_load_lds(
      (const __attribute__((address_space(1))) unsigned int*)g,
      (__attribute__((address_space(3))) unsigned int*)l, 16, 0, 0);
}

// ---------------- fp32 -> bf16 convert (vectorized) ----------------
__global__ void f32_to_bf16(const float* __restrict__ in, bf16* __restrict__ out, long n) {
  long i = ((long)blockIdx.x * blockDim.x + threadIdx.x) * 4;
  if (i >= n) return;
  float4 v = *(const float4*)(in + i);
  bf16 tmp[4] = {f2bf(v.x), f2bf(v.y), f2bf(v.z), f2bf(v.w)};
  *(uint2*)(out + i) = *(uint2*)tmp;
}

// ---------------- RoPE table ----------------
__global__ void rope_table(float* __restrict__ ct, float* __restrict__ st) {
  int idx = blockIdx.x * 256 + threadIdx.x;
  if (idx >= SEQ * 64) return;
  int j = idx & 63, n = idx >> 6;
  double inv = exp(-(double)j / 64.0 * 9.210340371976184); // 10000^{-j/64}
  double a = (double)n * inv;
  ct[idx] = (float)cos(a);
  st[idx] = (float)sin(a);
}

// ---------------- GEMM: C[M,N] = A[M,K] * B[N,K]^T (+bias) ----------------
// m97 structure: 128x128 tile, BK=32, 4 waves each 64x64, global_load_lds width 16.
template <int OUT_BF16>
__global__ __launch_bounds__(256) void gemm_bt(const bf16* __restrict__ A,
                                               const bf16* __restrict__ Bm,
                                               void* __restrict__ Cv,
                                               const float* __restrict__ bias,
                                               int M, int Nn, int K) {
  __shared__ alignas(16) bf16 lsA[128 * 32];
  __shared__ alignas(16) bf16 lsB[128 * 32];
  const int tid = threadIdx.x;
  const int wv = tid >> 6, ln = tid & 63;
  const long am0 = (long)blockIdx.y * 128;
  const long bn0 = (long)blockIdx.x * 128;
  const int wr = (wv >> 1) * 64, wc = (wv & 1) * 64;
  const int fr = ln & 15;
  const int fk = (ln >> 4) * 8;
  const int srow = ln >> 2;          // staging row within 16-row chunk
  const int scb  = (ln & 3) * 16;    // staging byte col within 64B row
  f32x4 acc[4][4] = {};

  for (int kt = 0; kt < K; kt += 32) {
    __syncthreads();
#pragma unroll
    for (int cc = 0; cc < 4; ++cc) {
      const int chunk = wv * 4 + cc;           // 0..7 -> A, 8..15 -> B
      const int rr = (chunk & 7) * 16 + srow;
      const bf16* srcbase = (chunk < 8) ? (A + (am0 + rr) * (long)K + kt)
                                        : (Bm + (bn0 + rr) * (long)K + kt);
      bf16* dst = (chunk < 8) ? (lsA + chunk * 512) : (lsB + (chunk - 8) * 512);
      gl_lds16((const char*)srcbase + scb, dst);
    }
    __syncthreads();
    bf16x8 af[4], bfr[4];
#pragma unroll
    for (int i = 0; i < 4; ++i)
      af[i] = *(const bf16x8*)(lsA + (wr + i * 16 + fr) * 32 + fk);
#pragma unroll
    for (int j = 0; j < 4; ++j)
      bfr[j] = *(const bf16x8*)(lsB + (wc + j * 16 + fr) * 32 + fk);
#pragma unroll
    for (int i = 0; i < 4; ++i)
#pragma unroll
      for (int j = 0; j < 4; ++j)
        acc[i][j] = __builtin_amdgcn_mfma_f32_16x16x32_bf16(af[i], bfr[j], acc[i][j], 0, 0, 0);
  }

#pragma unroll
  for (int i = 0; i < 4; ++i) {
#pragma unroll
    for (int j = 0; j < 4; ++j) {
      const long col = bn0 + wc + j * 16 + (ln & 15);
      const float bv = bias ? bias[col] : 0.f;
#pragma unroll
      for (int q = 0; q < 4; ++q) {
        const long row = am0 + wr + i * 16 + (ln >> 4) * 4 + q;
        const float v = acc[i][j][q] + bv;
        if (OUT_BF16) ((bf16*)Cv)[row * Nn + col] = f2bf(v);
        else          ((float*)Cv)[row * Nn + col] = v;
      }
    }
  }
}

// ---------------- RoPE + head reshape: qkv[4096,6144] -> q_r/k_r [bh, n, 128] ----------------
__global__ void rope_reshape(const bf16* __restrict__ qkv, const float* __restrict__ ct,
                             const float* __restrict__ st, bf16* __restrict__ q_r,
                             bf16* __restrict__ k_r) {
  long idx = (long)blockIdx.x * 256 + threadIdx.x; // = ((b*SEQ+n)*H + h)*64 + j
  int j = idx & 63;
  int h = (idx >> 6) & 15;
  int n = (idx >> 10) & 2047;
  int b = (int)(idx >> 21);
  long row = (long)b * SEQ + n;
  float c = ct[n * 64 + j], s = st[n * 64 + j];
  long qoff = row * EQ + h * 128 + j;
  float q1 = bf2f(qkv[qoff]),        q2 = bf2f(qkv[qoff + 64]);
  float k1 = bf2f(qkv[qoff + 2048]), k2 = bf2f(qkv[qoff + 2048 + 64]);
  long obase = ((long)(b * 16 + h) * SEQ + n) * HD + j;
  q_r[obase]      = f2bf((q1 * c - q2 * s) * QSCALE);
  q_r[obase + 64] = f2bf((q1 * s + q2 * c) * QSCALE);
  k_r[obase]      = f2bf(k1 * c - k2 * s);
  k_r[obase + 64] = f2bf(k1 * s + k2 * c);
}

// ---------------- V transpose: qkv v-part -> v_t [bh, d(128), n(2048)] ----------------
__global__ __launch_bounds__(256) void v_transpose(const bf16* __restrict__ qkv,
                                                   bf16* __restrict__ v_t) {
  __shared__ bf16 tile[64][65];
  int bh = blockIdx.z;
  int b = bh >> 4, h = bh & 15;
  int n0 = blockIdx.y * 64, d0 = blockIdx.x * 64;
  int t = threadIdx.x;
#pragma unroll
  for (int p = 0; p < 16; ++p) {
    int e = p * 256 + t;
    int dn = e & 63, nn = e >> 6;
    tile[nn][dn] = qkv[(long)(b * SEQ + n0 + nn) * EQ + 2 * DM + h * 128 + d0 + dn];
  }
  __syncthreads();
#pragma unroll
  for (int p = 0; p < 16; ++p) {
    int e = p * 256 + t;
    int nn = e & 63, dd = e >> 6;
    v_t[((long)bh * HD + d0 + dd) * SEQ + n0 + nn] = tile[nn][dd];
  }
}

// ---------------- Flash attention ----------------
// block = 4 waves; each wave owns 16 q-rows. KV tiles of 64. K/V staged via
// global_load_lds with pre-swizzled global source (XOR (row&7)<<4 on 16B slots).
__global__ __launch_bounds__(256) void attn_fwd(const bf16* __restrict__ q_r,
                                                const bf16* __restrict__ k_r,
                                                const bf16* __restrict__ v_t,
                                                bf16* __restrict__ ao) {
  __shared__ alignas(16) bf16 kt_s[64 * 128];   // [kv][256B] swizzled
  __shared__ alignas(16) bf16 vt_s[128 * 64];   // [d][128B]  swizzled
  __shared__ alignas(16) bf16 pt_s[4][16 * 64]; // per-wave P, [q][128B] swizzled

  const int bh = blockIdx.y;
  const int qt = blockIdx.x;
  const int wv = threadIdx.x >> 6, ln = threadIdx.x & 63;
  const int b = bh >> 4, h = bh & 15;
  const int q0 = qt * 64 + wv * 16;
  const int fr = ln & 15;
  const int fkb = (ln >> 4) * 16; // frag k byte offset

  // Q fragments in registers for the whole KV loop
  bf16x8 aq[4];
  const char* qrow = (const char*)(q_r + ((long)bh * SEQ + q0 + fr) * HD);
#pragma unroll
  for (int kc = 0; kc < 4; ++kc)
    aq[kc] = *(const bf16x8*)(qrow + kc * 64 + fkb);

  f32x4 oacc[8] = {};
  float mrow[4] = {-1e30f, -1e30f, -1e30f, -1e30f};
  float lsum[4] = {0.f, 0.f, 0.f, 0.f};

  for (int t = 0; t < SEQ / 64; ++t) {
    __syncthreads();
#pragma unroll
    for (int cc = 0; cc < 8; ++cc) {
      const int chunk = wv * 8 + cc; // 0..15 K-tile, 16..31 V-tile
      if (chunk < 16) {
        const int r = chunk * 4 + (ln >> 4);
        const int cb = ((ln & 15) * 16) ^ ((r & 7) << 4);
        const char* src = (const char*)k_r + ((long)bh * SEQ + t * 64 + r) * 256 + cb;
        gl_lds16(src, (char*)kt_s + chunk * 1024);
      } else {
        const int c2 = chunk - 16;
        const int d = c2 * 8 + (ln >> 3);
        const int cb = ((ln & 7) * 16) ^ ((d & 7) << 4);
        const char* src = (const char*)v_t + ((long)bh * HD + d) * (SEQ * 2) + t * 128 + cb;
        gl_lds16(src, (char*)vt_s + c2 * 1024);
      }
    }
    __syncthreads();

    // S = Q K^T  (16 q-rows x 64 kv)
    f32x4 s[4] = {};
#pragma unroll
    for (int kc = 0; kc < 4; ++kc) {
#pragma unroll
      for (int nf = 0; nf < 4; ++nf) {
        const int kvr = nf * 16 + fr;
        const int cb = (kc * 64 + fkb) ^ ((kvr & 7) << 4);
        bf16x8 bk = *(const bf16x8*)((const char*)kt_s + kvr * 256 + cb);
        s[nf] = __builtin_amdgcn_mfma_f32_16x16x32_bf16(aq[kc], bk, s[nf], 0, 0, 0);
      }
    }

    // online softmax; lane's rows are (ln>>4)*4 + i
    float sc[4];
#pragma unroll
    for (int i = 0; i < 4; ++i) {
      float mx = fmaxf(fmaxf(s[0][i], s[1][i]), fmaxf(s[2][i], s[3][i]));
#pragma unroll
      for (int off = 1; off < 16; off <<= 1)
        mx = fmaxf(mx, __shfl_xor(mx, off, 64));
      const float mn = fmaxf(mrow[i], mx);
      sc[i] = __expf(mrow[i] - mn);
      mrow[i] = mn;
      float ps = 0.f;
#pragma unroll
      for (int nf = 0; nf < 4; ++nf) {
        const float p = __expf(s[nf][i] - mn);
        s[nf][i] = p;
        ps += p;
      }
#pragma unroll
      for (int off = 1; off < 16; off <<= 1)
        ps += __shfl_xor(ps, off, 64);
      lsum[i] = lsum[i] * sc[i] + ps;
    }
#pragma unroll
    for (int nf = 0; nf < 8; ++nf)
#pragma unroll
      for (int i = 0; i < 4; ++i)
        oacc[nf][i] *= sc[i];

    // P (C-layout) -> per-wave LDS tile (bf16, swizzled), then read as A-frags
    char* pb = (char*)&pt_s[wv][0];
#pragma unroll
    for (int nf = 0; nf < 4; ++nf) {
#pragma unroll
      for (int i = 0; i < 4; ++i) {
        const int r = (ln >> 4) * 4 + i;
        const int cb = ((nf * 16 + fr) * 2) ^ ((r & 7) << 4);
        *(bf16*)(pb + r * 128 + cb) = f2bf(s[nf][i]);
      }
    }

    // O += P V
#pragma unroll
    for (int c2 = 0; c2 < 2; ++c2) {
      const int cbp = (c2 * 64 + fkb) ^ ((fr & 7) << 4);
      bf16x8 pa = *(const bf16x8*)(pb + fr * 128 + cbp);
#pragma unroll
      for (int nf = 0; nf < 8; ++nf) {
        const int d = nf * 16 + fr;
        const int cbv = (c2 * 64 + fkb) ^ ((d & 7) << 4);
        bf16x8 bv = *(const bf16x8*)((const char*)vt_s + d * 128 + cbv);
        oacc[nf] = __builtin_amdgcn_mfma_f32_16x16x32_bf16(pa, bv, oacc[nf], 0, 0, 0);
      }
    }
  }

  // epilogue: ao[b, n, h*128+d] = O / lsum
#pragma unroll
  for (int nf = 0; nf < 8; ++nf) {
#pragma unroll
    for (int i = 0; i < 4; ++i) {
      const int nrow = q0 + (ln >> 4) * 4 + i;
      const int dcol = h * 128 + nf * 16 + fr;
      ao[((long)b * SEQ + nrow) * DM + dcol] = f2bf(oacc[nf][i] / lsum[i]);
    }
  }
}

// ---------------- launch ----------------
extern "C" void kernel_launch(void* const* d_in, const int* in_sizes, int n_in,
                              void* d_out, int out_size, void* d_ws, size_t ws_size,
                              hipStream_t stream) {
  const float* x      = (const float*)d_in[0];
  const float* w_qkv  = (const float*)d_in[1];
  const float* w_proj = (const float*)d_in[2];
  const float* b_proj = (const float*)d_in[3];

  char* ws = (char*)d_ws;
  size_t off = 0;
  auto alloc = [&](size_t bytes) {
    void* p = ws + off;
    off += (bytes + 255) & ~(size_t)255;
    return p;
  };
  bf16* xb     = (bf16*)alloc((size_t)MROWS * DM * 2);
  bf16* wqkvb  = (bf16*)alloc((size_t)EQ * DM * 2);
  bf16* wprojb = (bf16*)alloc((size_t)DM * DM * 2);
  bf16* qkvb   = (bf16*)alloc((size_t)MROWS * EQ * 2);
  bf16* q_r    = (bf16*)alloc((size_t)Bz * H * SEQ * HD * 2);
  bf16* k_r    = (bf16*)alloc((size_t)Bz * H * SEQ * HD * 2);
  bf16* v_t    = (bf16*)alloc((size_t)Bz * H * SEQ * HD * 2);
  bf16* aob    = (bf16*)alloc((size_t)MROWS * DM * 2);
  float* ct    = (float*)alloc((size_t)SEQ * 64 * 4);
  float* st    = (float*)alloc((size_t)SEQ * 64 * 4);

  {
    long n = MROWS * DM;
    f32_to_bf16<<<(int)((n / 4 + 255) / 256), 256, 0, stream>>>(x, xb, n);
  }
  {
    long n = (long)EQ * DM;
    f32_to_bf16<<<(int)((n / 4 + 255) / 256), 256, 0, stream>>>(w_qkv, wqkvb, n);
  }
  {
    long n = (long)DM * DM;
    f32_to_bf16<<<(int)((n / 4 + 255) / 256), 256, 0, stream>>>(w_proj, wprojb, n);
  }
  rope_table<<<(SEQ * 64) / 256, 256, 0, stream>>>(ct, st);

  gemm_bt<1><<<dim3(EQ / 128, (int)(MROWS / 128)), 256, 0, stream>>>(
      xb, wqkvb, qkvb, nullptr, (int)MROWS, EQ, DM);

  rope_reshape<<<(int)((long)Bz * SEQ * H * 64 / 256), 256, 0, stream>>>(qkvb, ct, st, q_r, k_r);
  v_transpose<<<dim3(HD / 64, SEQ / 64, Bz * H), 256, 0, stream>>>(qkvb, v_t);

  attn_fwd<<<dim3(SEQ / 64, Bz * H), 256, 0, stream>>>(q_r, k_r, v_t, aob);

  gemm_bt<0><<<dim3(DM / 128, (int)(MROWS / 128)), 256, 0, stream>>>(
      aob, wprojb, d_out, b_proj, (int)MROWS, DM, DM);
}

// Round 2
// 348.660 us; speedup vs baseline: 1.2080x; 1.2080x over previous
//
#include <hip/hip_runtime.h>
#include <hip/hip_bf16.h>

using bf16 = __hip_bfloat16;
typedef __attribute__((ext_vector_type(8))) short bf16x8;
typedef __attribute__((ext_vector_type(4))) float f32x4;
typedef __attribute__((ext_vector_type(16))) float f32x16;
typedef __attribute__((ext_vector_type(4))) unsigned int u32x4;

constexpr int Bz  = 2;
constexpr int SEQ = 2048;
constexpr int DM  = 2048;
constexpr int H   = 16;
constexpr int HD  = 128;
constexpr long MROWS = (long)Bz * SEQ;   // 4096
constexpr int EQ  = 3 * DM;              // 6144
// 1/sqrt(128) * log2(e): fold softmax base-2 conversion into Q scaling
constexpr float QSCALE_L2E = 0.12751743427795914f;

__device__ __forceinline__ float bf2f(bf16 x) { return __bfloat162float(x); }
__device__ __forceinline__ bf16  f2bf(float x) { return __float2bfloat16(x); }

__device__ __forceinline__ float fexp2(float x) {
  float r;
  asm("v_exp_f32 %0, %1" : "=v"(r) : "v"(x));
  return r;
}

__device__ __forceinline__ void gl_lds16(const void* g, void* l) {
  __builtin_amdgcn_global_load_lds(
      (const __attribute__((address_space(1))) unsigned int*)g,
      (__attribute__((address_space(3))) unsigned int*)l, 16, 0, 0);
}

// ---------------- fp32 -> bf16 convert (vectorized) ----------------
__global__ void f32_to_bf16(const float* __restrict__ in, bf16* __restrict__ out, long n) {
  long i = ((long)blockIdx.x * blockDim.x + threadIdx.x) * 4;
  if (i >= n) return;
  float4 v = *(const float4*)(in + i);
  bf16 tmp[4] = {f2bf(v.x), f2bf(v.y), f2bf(v.z), f2bf(v.w)};
  *(uint2*)(out + i) = *(uint2*)tmp;
}

// ---------------- RoPE table ----------------
__global__ void rope_table(float* __restrict__ ct, float* __restrict__ st) {
  int idx = blockIdx.x * 256 + threadIdx.x;
  if (idx >= SEQ * 64) return;
  int j = idx & 63, n = idx >> 6;
  double inv = exp(-(double)j / 64.0 * 9.210340371976184); // 10000^{-j/64}
  double a = (double)n * inv;
  ct[idx] = (float)cos(a);
  st[idx] = (float)sin(a);
}

// ---------------- GEMM: C[M,N] = A[M,K] * B[N,K]^T (+bias) ----------------
template <int OUT_BF16>
__global__ __launch_bounds__(256) void gemm_bt(const bf16* __restrict__ A,
                                               const bf16* __restrict__ Bm,
                                               void* __restrict__ Cv,
                                               const float* __restrict__ bias,
                                               int M, int Nn, int K) {
  __shared__ alignas(16) bf16 lsA[128 * 32];
  __shared__ alignas(16) bf16 lsB[128 * 32];
  const int tid = threadIdx.x;
  const int wv = tid >> 6, ln = tid & 63;
  const long am0 = (long)blockIdx.y * 128;
  const long bn0 = (long)blockIdx.x * 128;
  const int wr = (wv >> 1) * 64, wc = (wv & 1) * 64;
  const int fr = ln & 15;
  const int fk = (ln >> 4) * 8;
  const int srow = ln >> 2;
  const int scb  = (ln & 3) * 16;
  f32x4 acc[4][4] = {};

  for (int kt = 0; kt < K; kt += 32) {
    __syncthreads();
#pragma unroll
    for (int cc = 0; cc < 4; ++cc) {
      const int chunk = wv * 4 + cc;
      const int rr = (chunk & 7) * 16 + srow;
      const bf16* srcbase = (chunk < 8) ? (A + (am0 + rr) * (long)K + kt)
                                        : (Bm + (bn0 + rr) * (long)K + kt);
      bf16* dst = (chunk < 8) ? (lsA + chunk * 512) : (lsB + (chunk - 8) * 512);
      gl_lds16((const char*)srcbase + scb, dst);
    }
    __syncthreads();
    bf16x8 af[4], bfr[4];
#pragma unroll
    for (int i = 0; i < 4; ++i)
      af[i] = *(const bf16x8*)(lsA + (wr + i * 16 + fr) * 32 + fk);
#pragma unroll
    for (int j = 0; j < 4; ++j)
      bfr[j] = *(const bf16x8*)(lsB + (wc + j * 16 + fr) * 32 + fk);
#pragma unroll
    for (int i = 0; i < 4; ++i)
#pragma unroll
      for (int j = 0; j < 4; ++j)
        acc[i][j] = __builtin_amdgcn_mfma_f32_16x16x32_bf16(af[i], bfr[j], acc[i][j], 0, 0, 0);
  }

#pragma unroll
  for (int i = 0; i < 4; ++i) {
#pragma unroll
    for (int j = 0; j < 4; ++j) {
      const long col = bn0 + wc + j * 16 + (ln & 15);
      const float bv = bias ? bias[col] : 0.f;
#pragma unroll
      for (int q = 0; q < 4; ++q) {
        const long row = am0 + wr + i * 16 + (ln >> 4) * 4 + q;
        const float v = acc[i][j][q] + bv;
        if (OUT_BF16) ((bf16*)Cv)[row * Nn + col] = f2bf(v);
        else          ((float*)Cv)[row * Nn + col] = v;
      }
    }
  }
}

// ---------------- RoPE + head reshape ----------------
__global__ void rope_reshape(const bf16* __restrict__ qkv, const float* __restrict__ ct,
                             const float* __restrict__ st, bf16* __restrict__ q_r,
                             bf16* __restrict__ k_r) {
  long idx = (long)blockIdx.x * 256 + threadIdx.x;
  int j = idx & 63;
  int h = (idx >> 6) & 15;
  int n = (idx >> 10) & 2047;
  int b = (int)(idx >> 21);
  long row = (long)b * SEQ + n;
  float c = ct[n * 64 + j], s = st[n * 64 + j];
  long qoff = row * EQ + h * 128 + j;
  float q1 = bf2f(qkv[qoff]),        q2 = bf2f(qkv[qoff + 64]);
  float k1 = bf2f(qkv[qoff + 2048]), k2 = bf2f(qkv[qoff + 2048 + 64]);
  long obase = ((long)(b * 16 + h) * SEQ + n) * HD + j;
  q_r[obase]      = f2bf((q1 * c - q2 * s) * QSCALE_L2E);
  q_r[obase + 64] = f2bf((q1 * s + q2 * c) * QSCALE_L2E);
  k_r[obase]      = f2bf(k1 * c - k2 * s);
  k_r[obase + 64] = f2bf(k1 * s + k2 * c);
}

// ---------------- V transpose: qkv v-part -> v_t [bh, d(128), n(2048)] ----------------
__global__ __launch_bounds__(256) void v_transpose(const bf16* __restrict__ qkv,
                                                   bf16* __restrict__ v_t) {
  __shared__ bf16 tile[64][65];
  int bh = blockIdx.z;
  int b = bh >> 4, h = bh & 15;
  int n0 = blockIdx.y * 64, d0 = blockIdx.x * 64;
  int t = threadIdx.x;
#pragma unroll
  for (int p = 0; p < 16; ++p) {
    int e = p * 256 + t;
    int dn = e & 63, nn = e >> 6;
    tile[nn][dn] = qkv[(long)(b * SEQ + n0 + nn) * EQ + 2 * DM + h * 128 + d0 + dn];
  }
  __syncthreads();
#pragma unroll
  for (int p = 0; p < 16; ++p) {
    int e = p * 256 + t;
    int nn = e & 63, dd = e >> 6;
    v_t[((long)bh * HD + d0 + dd) * SEQ + n0 + nn] = tile[nn][dd];
  }
}

// ---------------- Flash attention, swapped-QK^T 32x32 structure ----------------
// 4 waves x 32 q-rows = 128 q/block. KVBLK=64, double-buffered K/V in LDS.
// S^T = mfma(K,Q): lane owns one q-row -> in-register softmax.
// O^T = mfma(V^T, P): P stays in registers (half-exchange via shfl_xor 32).
__global__ __launch_bounds__(256, 2) void attn_fwd(const bf16* __restrict__ q_r,
                                                   const bf16* __restrict__ k_r,
                                                   const bf16* __restrict__ v_t,
                                                   bf16* __restrict__ ao) {
  __shared__ alignas(16) char lds[65536];
  // layout: kbuf0 [0,16K) kbuf1 [16K,32K) vbuf0 [32K,48K) vbuf1 [48K,64K)

  // XCD-aware remap: all 16 q-tiles of one (b,h) on one XCD (4MB KV = L2)
  const int flat = blockIdx.y * gridDim.x + blockIdx.x;   // 0..511
  const int bh = (flat & 7) * 4 + ((flat >> 3) >> 4);
  const int qt = (flat >> 3) & 15;
  const int b = bh >> 4, h = bh & 15;

  const int wv = threadIdx.x >> 6, ln = threadIdx.x & 63;
  const int lh = ln >> 5;        // lane half
  const int lq = ln & 31;        // this lane's q within the wave tile
  const int q0 = qt * 128 + wv * 32;

  // Q fragments (held all loop): Q[q0+lq][d], 8 k-subtiles of 16
  bf16x8 aq[8];
  {
    const char* qbase = (const char*)(q_r + ((long)bh * SEQ + q0 + lq) * HD);
#pragma unroll
    for (int ks = 0; ks < 8; ++ks)
      aq[ks] = *(const bf16x8*)(qbase + ks * 32 + lh * 16);
  }

  f32x16 oacc[4] = {};   // O^T: 4 d-tiles of 32, col=q
  float mrow = -1e30f, lsum = 0.f;

  auto stage = [&](int buf, int t) {
    char* kb = lds + buf * 16384;
    char* vb = lds + 32768 + buf * 16384;
#pragma unroll
    for (int cc = 0; cc < 8; ++cc) {
      const int chunk = wv * 8 + cc;          // 0..15 K, 16..31 V
      if (chunk < 16) {
        const int r = chunk * 4 + (ln >> 4);  // kv row 0..63
        const char* src = (const char*)k_r + ((long)bh * SEQ + t * 64 + r) * 256 +
                          (((ln & 15) ^ (r & 15)) << 4);
        gl_lds16(src, kb + chunk * 1024);
      } else {
        const int c2 = chunk - 16;
        const int r = c2 * 8 + (ln >> 3);     // d row 0..127
        const char* src = (const char*)v_t + ((long)bh * HD + r) * (SEQ * 2) + t * 128 +
                          (((ln & 7) ^ (r & 7)) << 4);
        gl_lds16(src, vb + c2 * 1024);
      }
    }
  };

  stage(0, 0);
  __syncthreads();

  for (int t = 0; t < SEQ / 64; ++t) {
    const int cur = t & 1;
    if (t + 1 < SEQ / 64) stage(cur ^ 1, t + 1);
    const char* kb = lds + cur * 16384;
    const char* vb = lds + 32768 + cur * 16384;

    // S^T = mfma(K, Q): sacc[kvs] covers kv rows kvs*32 + stripes
    f32x16 sacc[2] = {};
    __builtin_amdgcn_s_setprio(1);
#pragma unroll
    for (int kvs = 0; kvs < 2; ++kvs) {
      const int kv = kvs * 32 + lq;
#pragma unroll
      for (int ks = 0; ks < 8; ++ks) {
        bf16x8 kf = *(const bf16x8*)(kb + kv * 256 + ((((ks << 1) | lh) ^ (kv & 15)) << 4));
        sacc[kvs] = __builtin_amdgcn_mfma_f32_32x32x16_bf16(kf, aq[ks], sacc[kvs], 0, 0, 0);
      }
    }
    __builtin_amdgcn_s_setprio(0);

    // in-register online softmax (lane owns q = q0+lq; halves exchange via shfl 32)
    float mx = sacc[0][0];
#pragma unroll
    for (int r = 1; r < 16; ++r) mx = fmaxf(mx, sacc[0][r]);
#pragma unroll
    for (int r = 0; r < 16; ++r) mx = fmaxf(mx, sacc[1][r]);
    mx = fmaxf(mx, __shfl_xor(mx, 32, 64));
    const float mn = fmaxf(mrow, mx);
    const float scale = fexp2(mrow - mn);
    mrow = mn;
    float psum = 0.f;
#pragma unroll
    for (int k2 = 0; k2 < 2; ++k2)
#pragma unroll
      for (int r = 0; r < 16; ++r) {
        const float pv = fexp2(sacc[k2][r] - mn);
        sacc[k2][r] = pv;
        psum += pv;
      }
    psum += __shfl_xor(psum, 32, 64);
    lsum = lsum * scale + psum;
#pragma unroll
    for (int dt = 0; dt < 4; ++dt) oacc[dt] *= scale;

    // pack P -> bf16 A... (Y) frags: lane needs P[q][kv = kk*16 + lh*8 + e]
    bf16x8 pfrag[4];
#pragma unroll
    for (int k2 = 0; k2 < 2; ++k2) {
      unsigned int pk[8];
#pragma unroll
      for (int i = 0; i < 8; ++i) {
        unsigned int lo = __bfloat16_as_ushort(f2bf(sacc[k2][2 * i]));
        unsigned int hi = __bfloat16_as_ushort(f2bf(sacc[k2][2 * i + 1]));
        pk[i] = lo | (hi << 16);
      }
#pragma unroll
      for (int fb = 0; fb < 2; ++fb) {
        const unsigned int a0 = pk[fb * 4 + 0], a1 = pk[fb * 4 + 1];
        const unsigned int b0 = pk[fb * 4 + 2], b1 = pk[fb * 4 + 3];
        const unsigned int sb0 = __shfl_xor(b0, 32, 64);
        const unsigned int sb1 = __shfl_xor(b1, 32, 64);
        const unsigned int sa0 = __shfl_xor(a0, 32, 64);
        const unsigned int sa1 = __shfl_xor(a1, 32, 64);
        u32x4 wvec;
        wvec.x = lh ? sb0 : a0;   // kv(0,1) | kv(8,9)
        wvec.y = lh ? sb1 : a1;   // kv(2,3) | kv(10,11)
        wvec.z = lh ? b0 : sa0;   // kv(4,5) | kv(12,13)
        wvec.w = lh ? b1 : sa1;   // kv(6,7) | kv(14,15)
        pfrag[k2 * 2 + fb] = __builtin_bit_cast(bf16x8, wvec);
      }
    }

    // O^T += mfma(V^T, P)
    __builtin_amdgcn_s_setprio(1);
#pragma unroll
    for (int dt = 0; dt < 4; ++dt) {
      const int d = dt * 32 + lq;
#pragma unroll
      for (int kk = 0; kk < 4; ++kk) {
        bf16x8 vf = *(const bf16x8*)(vb + d * 128 + ((((kk << 1) | lh) ^ (d & 7)) << 4));
        oacc[dt] = __builtin_amdgcn_mfma_f32_32x32x16_bf16(vf, pfrag[kk], oacc[dt], 0, 0, 0);
      }
    }
    __builtin_amdgcn_s_setprio(0);
    __syncthreads();
  }

  // epilogue: O^T -> LDS transpose (row-per-q, pad to 132) -> coalesced store
  const float inv = 1.0f / lsum;
  bf16* ob = (bf16*)lds;
  const int qloc = wv * 32 + lq;
#pragma unroll
  for (int dt = 0; dt < 4; ++dt)
#pragma unroll
    for (int r = 0; r < 16; ++r) {
      const int d = dt * 32 + (r & 3) + 8 * (r >> 2) + 4 * lh;
      ob[qloc * 132 + d] = f2bf(oacc[dt][r] * inv);
    }
  // same-wave readback (rows are wave-exclusive), vectorized global store
#pragma unroll
  for (int it = 0; it < 8; ++it) {
    const int c = it * 64 + ln;
    const int qq = c >> 4, dc = c & 15;
    const char* srcp = (const char*)ob + (wv * 32 + qq) * 264 + dc * 16;
    uint2 v0 = *(const uint2*)srcp;
    uint2 v1 = *(const uint2*)(srcp + 8);
    uint4 outv;
    outv.x = v0.x; outv.y = v0.y; outv.z = v1.x; outv.w = v1.y;
    *(uint4*)((char*)(ao + ((long)b * SEQ + qt * 128 + wv * 32 + qq) * DM + h * 128) + dc * 16) = outv;
  }
}

// ---------------- launch ----------------
extern "C" void kernel_launch(void* const* d_in, const int* in_sizes, int n_in,
                              void* d_out, int out_size, void* d_ws, size_t ws_size,
                              hipStream_t stream) {
  const float* x      = (const float*)d_in[0];
  const float* w_qkv  = (const float*)d_in[1];
  const float* w_proj = (const float*)d_in[2];
  const float* b_proj = (const float*)d_in[3];

  char* ws = (char*)d_ws;
  size_t off = 0;
  auto alloc = [&](size_t bytes) {
    void* p = ws + off;
    off += (bytes + 255) & ~(size_t)255;
    return p;
  };
  bf16* xb     = (bf16*)alloc((size_t)MROWS * DM * 2);
  bf16* wqkvb  = (bf16*)alloc((size_t)EQ * DM * 2);
  bf16* wprojb = (bf16*)alloc((size_t)DM * DM * 2);
  bf16* qkvb   = (bf16*)alloc((size_t)MROWS * EQ * 2);
  bf16* q_r    = (bf16*)alloc((size_t)Bz * H * SEQ * HD * 2);
  bf16* k_r    = (bf16*)alloc((size_t)Bz * H * SEQ * HD * 2);
  bf16* v_t    = (bf16*)alloc((size_t)Bz * H * SEQ * HD * 2);
  bf16* aob    = (bf16*)alloc((size_t)MROWS * DM * 2);
  float* ct    = (float*)alloc((size_t)SEQ * 64 * 4);
  float* st    = (float*)alloc((size_t)SEQ * 64 * 4);

  {
    long n = MROWS * DM;
    f32_to_bf16<<<(int)((n / 4 + 255) / 256), 256, 0, stream>>>(x, xb, n);
  }
  {
    long n = (long)EQ * DM;
    f32_to_bf16<<<(int)((n / 4 + 255) / 256), 256, 0, stream>>>(w_qkv, wqkvb, n);
  }
  {
    long n = (long)DM * DM;
    f32_to_bf16<<<(int)((n / 4 + 255) / 256), 256, 0, stream>>>(w_proj, wprojb, n);
  }
  rope_table<<<(SEQ * 64) / 256, 256, 0, stream>>>(ct, st);

  gemm_bt<1><<<dim3(EQ / 128, (int)(MROWS / 128)), 256, 0, stream>>>(
      xb, wqkvb, qkvb, nullptr, (int)MROWS, EQ, DM);

  rope_reshape<<<(int)((long)Bz * SEQ * H * 64 / 256), 256, 0, stream>>>(qkvb, ct, st, q_r, k_r);
  v_transpose<<<dim3(HD / 64, SEQ / 64, Bz * H), 256, 0, stream>>>(qkvb, v_t);

  attn_fwd<<<dim3(16, Bz * H), 256, 0, stream>>>(q_r, k_r, v_t, aob);

  gemm_bt<0><<<dim3(DM / 128, (int)(MROWS / 128)), 256, 0, stream>>>(
      aob, wprojb, d_out, b_proj, (int)MROWS, DM, DM);
}